// Round 5
// baseline (138.165 us; speedup 1.0000x reference)
//
#include <hip/hip_runtime.h>
#include <hip/hip_bf16.h>
#include <math.h>

#define IMG 512
#define TW 64                     // output tile width
#define TH 32                     // output tile height
#define NTX 8                     // 512/64
#define NTY 16                    // 512/32
#define NIMG 48                   // 16*3
#define NBLOCKS (NTX * NTY * NIMG)   // 6144
#define NPIX (16LL * 3 * 512 * 512)

#define C1F 0.0001f
#define C2F 0.0009f

// R5: direct-from-global with MAX MEMORY-LEVEL PARALLELISM per wave.
// R0-R4 showed time==FETCH/2TB/s with VALUBusy pinned ~50% regardless of
// occupancy (33->62%) or barriers (staged vs direct): both structures
// serialize {load burst -> full vmcnt drain -> compute} — R1 at block
// granularity (barrier convoy), R4 at rg granularity (VGPR=48 proves the
// compiler never hoisted the 12 loads; 3 serial ~700cyc round-trips/wave).
// Fix: issue ALL 12 float4 loads first into named regs (48 VGPR held),
// cover latency with the B-fragment LDS gather, then consume rg0/1/2 in
// order => compiler emits counted vmcnt(8)/(4)/(0), one latency exposure
// per wave. launch_bounds(256,4): VGPR cap 128, no spill (WRITE_SIZE is
// the tripwire — R3's scratch disaster).
// Interior blocks (bx 1..6, by 1..14 = 65.6%) take a predicate-free path.

typedef __attribute__((ext_vector_type(4))) short short4v;
typedef __attribute__((ext_vector_type(8))) short short8;
typedef __attribute__((ext_vector_type(4))) float float4v;
typedef __attribute__((ext_vector_type(2))) unsigned uint2v;
typedef __attribute__((ext_vector_type(4))) unsigned uint4v;

// 16x16x16 bf16 MFMA (device-verified _1k builtin on gfx950; host parse stub).
__device__ __forceinline__ float4v mfma16(short4v a, short4v b, float4v c) {
#if defined(__HIP_DEVICE_COMPILE__)
    return __builtin_amdgcn_mfma_f32_16x16x16bf16_1k(a, b, c, 0, 0, 0);
#else
    return c;   // host stub — never executed
#endif
}

// Gaussian window (sigma=1.5, ws=11), normalized (double-derived literals).
#define GW0 0.00102838f
#define GW1 0.00759877f
#define GW2 0.03600077f
#define GW3 0.10936069f
#define GW4 0.21300539f
#define GW5 0.26601172f

__device__ __forceinline__ unsigned short f2bf(float f) {
    unsigned u = __builtin_bit_cast(unsigned, f);
    u += 0x7FFF + ((u >> 16) & 1);            // RNE
    return (unsigned short)(u >> 16);
}
__device__ __forceinline__ unsigned pk2(float a, float b) {
    __hip_bfloat162 h = __float22bfloat162_rn(make_float2(a, b));
    unsigned u;
    __builtin_memcpy(&u, &h, 4);
    return u;
}

#define BC4(U) __builtin_bit_cast(short4v, U)

// Predicated (or folded-away when IOK) 4x16B load block for one rg row.
#define LOAD_RG(ROW_EXPR, XF0, XF1, YF0, YF1)                                  \
    {                                                                          \
        const int gr_ = r00 + (ROW_EXPR);                                      \
        if (IOK || (colok && (unsigned)gr_ < 512u)) {                          \
            const size_t o_ = (size_t)gr_ * IMG + cbase;                       \
            XF0 = *(const float4*)(xi + o_);                                   \
            XF1 = *(const float4*)(xi + o_ + 4);                               \
            YF0 = *(const float4*)(yi + o_);                                   \
            YF1 = *(const float4*)(yi + o_ + 4);                               \
        }                                                                      \
    }

// Consume one rg: in-register bf16 channel build, 4 H-conv MFMAs into named
// uint2v destinations, owned-region L1 (q in {1,2}, srow in [5,36]).
#define CONSUME_RG(XF0, XF1, YF0, YF1, SROW_EXPR, DSTX, DSTY, DSTS, DSTP)      \
    {                                                                          \
        const int srow_ = (SROW_EXPR);                                         \
        uint4v ux_ = (uint4v){pk2(XF0.x, XF0.y), pk2(XF0.z, XF0.w),            \
                              pk2(XF1.x, XF1.y), pk2(XF1.z, XF1.w)};           \
        uint4v uy_ = (uint4v){pk2(YF0.x, YF0.y), pk2(YF0.z, YF0.w),            \
                              pk2(YF1.x, YF1.y), pk2(YF1.z, YF1.w)};           \
        uint4v u2_ = (uint4v){                                                 \
            pk2(fmaf(XF0.x,XF0.x,YF0.x*YF0.x), fmaf(XF0.y,XF0.y,YF0.y*YF0.y)), \
            pk2(fmaf(XF0.z,XF0.z,YF0.z*YF0.z), fmaf(XF0.w,XF0.w,YF0.w*YF0.w)), \
            pk2(fmaf(XF1.x,XF1.x,YF1.x*YF1.x), fmaf(XF1.y,XF1.y,YF1.y*YF1.y)), \
            pk2(fmaf(XF1.z,XF1.z,YF1.z*YF1.z), fmaf(XF1.w,XF1.w,YF1.w*YF1.w))};\
        uint4v u3_ = (uint4v){                                                 \
            pk2(XF0.x*YF0.x, XF0.y*YF0.y), pk2(XF0.z*YF0.z, XF0.w*YF0.w),      \
            pk2(XF1.x*YF1.x, XF1.y*YF1.y), pk2(XF1.z*YF1.z, XF1.w*YF1.w)};     \
        float4v d_;                                                            \
        d_ = __builtin_amdgcn_mfma_f32_16x16x32_bf16(                          \
                 __builtin_bit_cast(short8, ux_), bh, zero4, 0, 0, 0);         \
        DSTX = (uint2v){pk2(d_[0], d_[1]), pk2(d_[2], d_[3])};                 \
        d_ = __builtin_amdgcn_mfma_f32_16x16x32_bf16(                          \
                 __builtin_bit_cast(short8, uy_), bh, zero4, 0, 0, 0);         \
        DSTY = (uint2v){pk2(d_[0], d_[1]), pk2(d_[2], d_[3])};                 \
        d_ = __builtin_amdgcn_mfma_f32_16x16x32_bf16(                          \
                 __builtin_bit_cast(short8, u2_), bh, zero4, 0, 0, 0);         \
        DSTS = (uint2v){pk2(d_[0], d_[1]), pk2(d_[2], d_[3])};                 \
        d_ = __builtin_amdgcn_mfma_f32_16x16x32_bf16(                          \
                 __builtin_bit_cast(short8, u3_), bh, zero4, 0, 0, 0);         \
        DSTP = (uint2v){pk2(d_[0], d_[1]), pk2(d_[2], d_[3])};                 \
        if ((unsigned)(q - 1) <= 1u && (unsigned)(srow_ - 5) <= 31u)           \
            l1_loc += fabsf(XF0.x-YF0.x)+fabsf(XF0.y-YF0.y)                    \
                    + fabsf(XF0.z-YF0.z)+fabsf(XF0.w-YF0.w)                    \
                    + fabsf(XF1.x-YF1.x)+fabsf(XF1.y-YF1.y)                    \
                    + fabsf(XF1.z-YF1.z)+fabsf(XF1.w-YF1.w);                   \
    }

// SSIM epilogue over one float4v set.
#define SSIM_ACC(M1, M2, EE, PP)                                               \
    _Pragma("unroll")                                                          \
    for (int r_ = 0; r_ < 4; ++r_) {                                           \
        float mu1 = (M1)[r_], mu2 = (M2)[r_];                                  \
        float e   = (EE)[r_], e12 = (PP)[r_];                                  \
        float p = mu1 * mu2;                                                   \
        float s = fmaf(mu1, mu1, mu2 * mu2);                                   \
        float num1 = fmaf(2.f, p, C1F);                                        \
        float num2 = fmaf(2.f, e12 - p, C2F);                                  \
        float den1 = s + C1F;                                                  \
        float den2 = (e - s) + C2F;                                            \
        ssim_loc = fmaf(num1 * num2,                                           \
                        __builtin_amdgcn_rcpf(den1 * den2), ssim_loc);         \
    }

template<bool IOK>
__device__ __forceinline__ void tile_body(
    const float* __restrict__ xi, const float* __restrict__ yi,
    int r00, int cbase, bool colok,
    const unsigned short* gwtbl, int q, int n16,
    float& l1_loc, float& ssim_loc)
{
    const float4 zf = make_float4(0.f, 0.f, 0.f, 0.f);
    const float4v zero4 = {0.f, 0.f, 0.f, 0.f};

    // ---- Phase 1: issue ALL 12 loads (stay in flight across Phase 2) ----
    float4 xA0 = zf, xA1 = zf, yA0 = zf, yA1 = zf;
    float4 xB0 = zf, xB1 = zf, yB0 = zf, yB1 = zf;
    float4 xC0 = zf, xC1 = zf, yC0 = zf, yC1 = zf;
    LOAD_RG(n16,                xA0, xA1, yA0, yA1)
    LOAD_RG(16 + n16,           xB0, xB1, yB0, yB1)
    LOAD_RG(min(32 + n16, 41),  xC0, xC1, yC0, yC1)   // rows 42..47: zero v-taps

    // ---- Phase 2: B fragments from gwtbl (LDS gather covers HBM latency) --
    // h (K=32): Bh[k][n] = g[k-n-3], k = q*8+j
    // v chunk0 (K=16): Bv0[k][n] = g[k-n]; chunk1: Bv1[k][n] = g[k+16-n]
    short8 bh;
    short4v bv0, bv1;
    {
        int baseh = q * 8 - n16 - 3;
        #pragma unroll
        for (int j = 0; j < 8; ++j)
            bh[j] = (short)gwtbl[min((unsigned)(baseh + j), 15u)];
        int base0 = q * 4 - n16, base1 = q * 4 + 16 - n16;
        #pragma unroll
        for (int j = 0; j < 4; ++j) {
            bv0[j] = (short)gwtbl[min((unsigned)(base0 + j), 15u)];
            bv1[j] = (short)gwtbl[min((unsigned)(base1 + j), 15u)];
        }
    }

    // ---- Phase 3: consume in load order (counted vmcnt, single exposure) --
    uint2v d0x, d0y, d0s, d0p;
    uint2v e1x, e1y, e1s, e1p;
    uint2v f2x, f2y, f2s, f2p;
    CONSUME_RG(xA0, xA1, yA0, yA1, n16,      d0x, d0y, d0s, d0p)
    CONSUME_RG(xB0, xB1, yB0, yB1, 16 + n16, e1x, e1y, e1s, e1p)
    CONSUME_RG(xC0, xC1, yC0, yC1, 32 + n16, f2x, f2y, f2s, f2p)

    // ---- V-conv: acc = D1[rgp]·Bv0 + D1[rgp+1]·Bv1 (chained x16 MFMAs).
    //      Output: lane (q,n16) = out row rgp*16+n16, out cols w*16+q*4+r. --
    {   // rgp = 0
        float4v am1 = mfma16(BC4(d0x), bv0, mfma16(BC4(e1x), bv1, zero4));
        float4v am2 = mfma16(BC4(d0y), bv0, mfma16(BC4(e1y), bv1, zero4));
        float4v ae  = mfma16(BC4(d0s), bv0, mfma16(BC4(e1s), bv1, zero4));
        float4v ap  = mfma16(BC4(d0p), bv0, mfma16(BC4(e1p), bv1, zero4));
        SSIM_ACC(am1, am2, ae, ap)
    }
    {   // rgp = 1
        float4v bm1 = mfma16(BC4(e1x), bv0, mfma16(BC4(f2x), bv1, zero4));
        float4v bm2 = mfma16(BC4(e1y), bv0, mfma16(BC4(f2y), bv1, zero4));
        float4v be  = mfma16(BC4(e1s), bv0, mfma16(BC4(f2s), bv1, zero4));
        float4v bp  = mfma16(BC4(e1p), bv0, mfma16(BC4(f2p), bv1, zero4));
        SSIM_ACC(bm1, bm2, be, bp)
    }
}

__global__ __launch_bounds__(256, 4)
void ssim_tile_kernel(const float* __restrict__ xg, const float* __restrict__ yg,
                      float* __restrict__ partials) {
    __shared__ unsigned short gwtbl[16];            // bf16 taps, [11..15]=0
    __shared__ float red[8];

    const int tid  = threadIdx.x;
    const int lane = tid & 63;
    const int w    = tid >> 6;        // wave 0..3 = colgroup
    const int q    = lane >> 4;       // quad 0..3
    const int n16  = lane & 15;

    const int img = blockIdx.z;
    const int r00  = blockIdx.y * TH - 5;   // global row of staged-coords row 0
    const int c00a = blockIdx.x * TW - 8;   // global col of staged-coords col 0
    const float* __restrict__ xi = xg + (size_t)img * (IMG * IMG);
    const float* __restrict__ yi = yg + (size_t)img * (IMG * IMG);

    // ---- bf16 Gaussian tap table (compile-time-folded constants) ----
    if (tid < 16) {
        const float gwf[11] = {GW0, GW1, GW2, GW3, GW4, GW5, GW4, GW3, GW2, GW1, GW0};
        unsigned short v = 0;
        #pragma unroll
        for (int t = 0; t < 11; ++t)
            if (tid == t) v = f2bf(gwf[t]);
        gwtbl[tid] = v;
    }
    __syncthreads();   // publish gwtbl (no memory in flight yet)

    const int cbase = c00a + w * 16 + q * 8;
    const bool colok = (unsigned)cbase < 512u;
    // Interior: all staged rows [r00, r00+41] and cols [cbase, cbase+7] in
    // [0,512). bx in [1,6]: c00a>=56, max col 376+72+7=455. by in [1,14]:
    // r00>=27, r00+41<=484.
    const bool interior = ((unsigned)(blockIdx.x - 1) <= 5u) &
                          ((unsigned)(blockIdx.y - 1) <= 13u);

    float l1_loc = 0.f, ssim_loc = 0.f;
    if (interior)
        tile_body<true >(xi, yi, r00, cbase, colok, gwtbl, q, n16, l1_loc, ssim_loc);
    else
        tile_body<false>(xi, yi, r00, cbase, colok, gwtbl, q, n16, l1_loc, ssim_loc);

    // ---- Block reduction ----
    #pragma unroll
    for (int off = 32; off > 0; off >>= 1) {
        ssim_loc += __shfl_down(ssim_loc, off);
        l1_loc   += __shfl_down(l1_loc, off);
    }
    if (lane == 0) {
        red[w] = ssim_loc;
        red[4 + w] = l1_loc;
    }
    __syncthreads();
    if (tid == 0) {
        float ss = red[0] + red[1] + red[2] + red[3];
        float ll = red[4] + red[5] + red[6] + red[7];
        int bid = blockIdx.x + NTX * (blockIdx.y + NTY * blockIdx.z);
        partials[bid] = ss;
        partials[NBLOCKS + bid] = ll;
    }
}

__global__ __launch_bounds__(1024)
void finalize_kernel(const float* __restrict__ partials, float* __restrict__ out) {
    __shared__ double rs[16], rl[16];
    const int tid = threadIdx.x;
    double ss = 0.0, ll = 0.0;
    for (int i = tid; i < NBLOCKS; i += 1024) {
        ss += (double)partials[i];
        ll += (double)partials[NBLOCKS + i];
    }
    #pragma unroll
    for (int off = 32; off > 0; off >>= 1) {
        ss += __shfl_down(ss, off);
        ll += __shfl_down(ll, off);
    }
    int wave = tid >> 6, lane = tid & 63;
    if (lane == 0) { rs[wave] = ss; rl[wave] = ll; }
    __syncthreads();
    if (tid == 0) {
        double sst = 0.0, llt = 0.0;
        #pragma unroll
        for (int w = 0; w < 16; ++w) { sst += rs[w]; llt += rl[w]; }
        double invn = 1.0 / (double)NPIX;
        out[0] = (float)(llt * invn + (1.0 - sst * invn));
    }
}

extern "C" void kernel_launch(void* const* d_in, const int* in_sizes, int n_in,
                              void* d_out, int out_size, void* d_ws, size_t ws_size,
                              hipStream_t stream) {
    const float* x = (const float*)d_in[0];   // outputs
    const float* y = (const float*)d_in[1];   // labels
    float* out = (float*)d_out;
    float* partials = (float*)d_ws;           // 2*NBLOCKS*4 = 49,152 B

    dim3 grid(NTX, NTY, NIMG);
    ssim_tile_kernel<<<grid, dim3(256), 0, stream>>>(x, y, partials);
    finalize_kernel<<<1, dim3(1024), 0, stream>>>(partials, out);
}

// Round 6
// 137.721 us; speedup vs baseline: 1.0032x; 1.0032x over previous
//
#include <hip/hip_runtime.h>
#include <hip/hip_bf16.h>
#include <math.h>

#define IMG 512
#define TW 64                     // output tile width
#define TH 32                     // output tile height
#define NTX 8                     // 512/64
#define NTY 16                    // 512/32
#define NIMG 48                   // 16*3
#define NBLOCKS (NTX * NTY * NIMG)   // 6144
#define NPIX (16LL * 3 * 512 * 512)

#define C1F 0.0001f
#define C2F 0.0009f

// R6: R5 + sched_barrier(0) fences around the load phase.
// R5 post-mortem: VGPR_Count=52 proved the machine scheduler re-sank the 12
// loads into the consume blocks (pressure-directed), recreating 3-6 serial
// {load -> vmcnt(0) -> compute} segments; throughput model gives ~12k cyc
// effective latency per wave vs ~1k issue => latency exposure IS the wall
// (BW 30%, VALU ~20%, MFMA 8%: nothing else is). Source order does not
// survive hipcc (guide rule #18); __builtin_amdgcn_sched_barrier(0) does.
// Fence 1 after all 12 global_load_dwordx4 issues; fence 2 after the
// B-fragment LDS gather. Forces: loads | gather (covers latency) |
// counted vmcnt(8)/(4)/(0) consumes — ONE latency exposure per wave.
// VGPR: 48 in-flight data + 3 voffsets + taps + outputs ~ 100-110 < 128
// cap at launch_bounds(256,4). Tripwires: VGPR ~52 => fence defeated;
// WRITE_SIZE >> 1 MB => spill (R3's failure mode).

typedef __attribute__((ext_vector_type(4))) short short4v;
typedef __attribute__((ext_vector_type(8))) short short8;
typedef __attribute__((ext_vector_type(4))) float float4v;
typedef __attribute__((ext_vector_type(2))) unsigned uint2v;
typedef __attribute__((ext_vector_type(4))) unsigned uint4v;

// 16x16x16 bf16 MFMA (device-verified _1k builtin on gfx950; host parse stub).
__device__ __forceinline__ float4v mfma16(short4v a, short4v b, float4v c) {
#if defined(__HIP_DEVICE_COMPILE__)
    return __builtin_amdgcn_mfma_f32_16x16x16bf16_1k(a, b, c, 0, 0, 0);
#else
    return c;   // host stub — never executed
#endif
}

// Gaussian window (sigma=1.5, ws=11), normalized (double-derived literals).
#define GW0 0.00102838f
#define GW1 0.00759877f
#define GW2 0.03600077f
#define GW3 0.10936069f
#define GW4 0.21300539f
#define GW5 0.26601172f

__device__ __forceinline__ unsigned short f2bf(float f) {
    unsigned u = __builtin_bit_cast(unsigned, f);
    u += 0x7FFF + ((u >> 16) & 1);            // RNE
    return (unsigned short)(u >> 16);
}
__device__ __forceinline__ unsigned pk2(float a, float b) {
    __hip_bfloat162 h = __float22bfloat162_rn(make_float2(a, b));
    unsigned u;
    __builtin_memcpy(&u, &h, 4);
    return u;
}

#define BC4(U) __builtin_bit_cast(short4v, U)

// Predicated (or folded-away when IOK) 4x16B load block for one rg row.
#define LOAD_RG(ROW_EXPR, XF0, XF1, YF0, YF1)                                  \
    {                                                                          \
        const int gr_ = r00 + (ROW_EXPR);                                      \
        if (IOK || (colok && (unsigned)gr_ < 512u)) {                          \
            const size_t o_ = (size_t)gr_ * IMG + cbase;                       \
            XF0 = *(const float4*)(xi + o_);                                   \
            XF1 = *(const float4*)(xi + o_ + 4);                               \
            YF0 = *(const float4*)(yi + o_);                                   \
            YF1 = *(const float4*)(yi + o_ + 4);                               \
        }                                                                      \
    }

// Consume one rg: in-register bf16 channel build, 4 H-conv MFMAs into named
// uint2v destinations, owned-region L1 (q in {1,2}, srow in [5,36]).
#define CONSUME_RG(XF0, XF1, YF0, YF1, SROW_EXPR, DSTX, DSTY, DSTS, DSTP)      \
    {                                                                          \
        const int srow_ = (SROW_EXPR);                                         \
        uint4v ux_ = (uint4v){pk2(XF0.x, XF0.y), pk2(XF0.z, XF0.w),            \
                              pk2(XF1.x, XF1.y), pk2(XF1.z, XF1.w)};           \
        uint4v uy_ = (uint4v){pk2(YF0.x, YF0.y), pk2(YF0.z, YF0.w),            \
                              pk2(YF1.x, YF1.y), pk2(YF1.z, YF1.w)};           \
        uint4v u2_ = (uint4v){                                                 \
            pk2(fmaf(XF0.x,XF0.x,YF0.x*YF0.x), fmaf(XF0.y,XF0.y,YF0.y*YF0.y)), \
            pk2(fmaf(XF0.z,XF0.z,YF0.z*YF0.z), fmaf(XF0.w,XF0.w,YF0.w*YF0.w)), \
            pk2(fmaf(XF1.x,XF1.x,YF1.x*YF1.x), fmaf(XF1.y,XF1.y,YF1.y*YF1.y)), \
            pk2(fmaf(XF1.z,XF1.z,YF1.z*YF1.z), fmaf(XF1.w,XF1.w,YF1.w*YF1.w))};\
        uint4v u3_ = (uint4v){                                                 \
            pk2(XF0.x*YF0.x, XF0.y*YF0.y), pk2(XF0.z*YF0.z, XF0.w*YF0.w),      \
            pk2(XF1.x*YF1.x, XF1.y*YF1.y), pk2(XF1.z*YF1.z, XF1.w*YF1.w)};     \
        float4v d_;                                                            \
        d_ = __builtin_amdgcn_mfma_f32_16x16x32_bf16(                          \
                 __builtin_bit_cast(short8, ux_), bh, zero4, 0, 0, 0);         \
        DSTX = (uint2v){pk2(d_[0], d_[1]), pk2(d_[2], d_[3])};                 \
        d_ = __builtin_amdgcn_mfma_f32_16x16x32_bf16(                          \
                 __builtin_bit_cast(short8, uy_), bh, zero4, 0, 0, 0);         \
        DSTY = (uint2v){pk2(d_[0], d_[1]), pk2(d_[2], d_[3])};                 \
        d_ = __builtin_amdgcn_mfma_f32_16x16x32_bf16(                          \
                 __builtin_bit_cast(short8, u2_), bh, zero4, 0, 0, 0);         \
        DSTS = (uint2v){pk2(d_[0], d_[1]), pk2(d_[2], d_[3])};                 \
        d_ = __builtin_amdgcn_mfma_f32_16x16x32_bf16(                          \
                 __builtin_bit_cast(short8, u3_), bh, zero4, 0, 0, 0);         \
        DSTP = (uint2v){pk2(d_[0], d_[1]), pk2(d_[2], d_[3])};                 \
        if ((unsigned)(q - 1) <= 1u && (unsigned)(srow_ - 5) <= 31u)           \
            l1_loc += fabsf(XF0.x-YF0.x)+fabsf(XF0.y-YF0.y)                    \
                    + fabsf(XF0.z-YF0.z)+fabsf(XF0.w-YF0.w)                    \
                    + fabsf(XF1.x-YF1.x)+fabsf(XF1.y-YF1.y)                    \
                    + fabsf(XF1.z-YF1.z)+fabsf(XF1.w-YF1.w);                   \
    }

// SSIM epilogue over one float4v set.
#define SSIM_ACC(M1, M2, EE, PP)                                               \
    _Pragma("unroll")                                                          \
    for (int r_ = 0; r_ < 4; ++r_) {                                           \
        float mu1 = (M1)[r_], mu2 = (M2)[r_];                                  \
        float e   = (EE)[r_], e12 = (PP)[r_];                                  \
        float p = mu1 * mu2;                                                   \
        float s = fmaf(mu1, mu1, mu2 * mu2);                                   \
        float num1 = fmaf(2.f, p, C1F);                                        \
        float num2 = fmaf(2.f, e12 - p, C2F);                                  \
        float den1 = s + C1F;                                                  \
        float den2 = (e - s) + C2F;                                            \
        ssim_loc = fmaf(num1 * num2,                                           \
                        __builtin_amdgcn_rcpf(den1 * den2), ssim_loc);         \
    }

template<bool IOK>
__device__ __forceinline__ void tile_body(
    const float* __restrict__ xi, const float* __restrict__ yi,
    int r00, int cbase, bool colok,
    const unsigned short* gwtbl, int q, int n16,
    float& l1_loc, float& ssim_loc)
{
    const float4 zf = make_float4(0.f, 0.f, 0.f, 0.f);
    const float4v zero4 = {0.f, 0.f, 0.f, 0.f};

    // ---- Phase 1: issue ALL 12 loads ----
    float4 xA0 = zf, xA1 = zf, yA0 = zf, yA1 = zf;
    float4 xB0 = zf, xB1 = zf, yB0 = zf, yB1 = zf;
    float4 xC0 = zf, xC1 = zf, yC0 = zf, yC1 = zf;
    LOAD_RG(n16,                xA0, xA1, yA0, yA1)
    LOAD_RG(16 + n16,           xB0, xB1, yB0, yB1)
    LOAD_RG(min(32 + n16, 41),  xC0, xC1, yC0, yC1)   // rows 42..47: zero v-taps

#if defined(__HIP_DEVICE_COMPILE__)
    __builtin_amdgcn_sched_barrier(0);   // FENCE: nothing crosses — loads stay issued here
#endif

    // ---- Phase 2: B fragments from gwtbl (LDS gather covers HBM latency) --
    // h (K=32): Bh[k][n] = g[k-n-3], k = q*8+j
    // v chunk0 (K=16): Bv0[k][n] = g[k-n]; chunk1: Bv1[k][n] = g[k+16-n]
    short8 bh;
    short4v bv0, bv1;
    {
        int baseh = q * 8 - n16 - 3;
        #pragma unroll
        for (int j = 0; j < 8; ++j)
            bh[j] = (short)gwtbl[min((unsigned)(baseh + j), 15u)];
        int base0 = q * 4 - n16, base1 = q * 4 + 16 - n16;
        #pragma unroll
        for (int j = 0; j < 4; ++j) {
            bv0[j] = (short)gwtbl[min((unsigned)(base0 + j), 15u)];
            bv1[j] = (short)gwtbl[min((unsigned)(base1 + j), 15u)];
        }
    }

#if defined(__HIP_DEVICE_COMPILE__)
    __builtin_amdgcn_sched_barrier(0);   // FENCE: gather stays between loads and consumes
#endif

    // ---- Phase 3: consume in load order (counted vmcnt, single exposure) --
    uint2v d0x, d0y, d0s, d0p;
    uint2v e1x, e1y, e1s, e1p;
    uint2v f2x, f2y, f2s, f2p;
    CONSUME_RG(xA0, xA1, yA0, yA1, n16,      d0x, d0y, d0s, d0p)
    CONSUME_RG(xB0, xB1, yB0, yB1, 16 + n16, e1x, e1y, e1s, e1p)
    CONSUME_RG(xC0, xC1, yC0, yC1, 32 + n16, f2x, f2y, f2s, f2p)

    // ---- V-conv: acc = D1[rgp]·Bv0 + D1[rgp+1]·Bv1 (chained x16 MFMAs).
    //      Output: lane (q,n16) = out row rgp*16+n16, out cols w*16+q*4+r. --
    {   // rgp = 0
        float4v am1 = mfma16(BC4(d0x), bv0, mfma16(BC4(e1x), bv1, zero4));
        float4v am2 = mfma16(BC4(d0y), bv0, mfma16(BC4(e1y), bv1, zero4));
        float4v ae  = mfma16(BC4(d0s), bv0, mfma16(BC4(e1s), bv1, zero4));
        float4v ap  = mfma16(BC4(d0p), bv0, mfma16(BC4(e1p), bv1, zero4));
        SSIM_ACC(am1, am2, ae, ap)
    }
    {   // rgp = 1
        float4v bm1 = mfma16(BC4(e1x), bv0, mfma16(BC4(f2x), bv1, zero4));
        float4v bm2 = mfma16(BC4(e1y), bv0, mfma16(BC4(f2y), bv1, zero4));
        float4v be  = mfma16(BC4(e1s), bv0, mfma16(BC4(f2s), bv1, zero4));
        float4v bp  = mfma16(BC4(e1p), bv0, mfma16(BC4(f2p), bv1, zero4));
        SSIM_ACC(bm1, bm2, be, bp)
    }
}

__global__ __launch_bounds__(256, 4)
void ssim_tile_kernel(const float* __restrict__ xg, const float* __restrict__ yg,
                      float* __restrict__ partials) {
    __shared__ unsigned short gwtbl[16];            // bf16 taps, [11..15]=0
    __shared__ float red[8];

    const int tid  = threadIdx.x;
    const int lane = tid & 63;
    const int w    = tid >> 6;        // wave 0..3 = colgroup
    const int q    = lane >> 4;       // quad 0..3
    const int n16  = lane & 15;

    const int img = blockIdx.z;
    const int r00  = blockIdx.y * TH - 5;   // global row of staged-coords row 0
    const int c00a = blockIdx.x * TW - 8;   // global col of staged-coords col 0
    const float* __restrict__ xi = xg + (size_t)img * (IMG * IMG);
    const float* __restrict__ yi = yg + (size_t)img * (IMG * IMG);

    // ---- bf16 Gaussian tap table (compile-time-folded constants) ----
    if (tid < 16) {
        const float gwf[11] = {GW0, GW1, GW2, GW3, GW4, GW5, GW4, GW3, GW2, GW1, GW0};
        unsigned short v = 0;
        #pragma unroll
        for (int t = 0; t < 11; ++t)
            if (tid == t) v = f2bf(gwf[t]);
        gwtbl[tid] = v;
    }
    __syncthreads();   // publish gwtbl (no memory in flight yet — pre-load)

    const int cbase = c00a + w * 16 + q * 8;
    const bool colok = (unsigned)cbase < 512u;
    // Interior: all staged rows [r00, r00+41] and cols [cbase, cbase+7] in
    // [0,512). bx in [1,6], by in [1,14].
    const bool interior = ((unsigned)(blockIdx.x - 1) <= 5u) &
                          ((unsigned)(blockIdx.y - 1) <= 13u);

    float l1_loc = 0.f, ssim_loc = 0.f;
    if (interior)
        tile_body<true >(xi, yi, r00, cbase, colok, gwtbl, q, n16, l1_loc, ssim_loc);
    else
        tile_body<false>(xi, yi, r00, cbase, colok, gwtbl, q, n16, l1_loc, ssim_loc);

    // ---- Block reduction ----
    #pragma unroll
    for (int off = 32; off > 0; off >>= 1) {
        ssim_loc += __shfl_down(ssim_loc, off);
        l1_loc   += __shfl_down(l1_loc, off);
    }
    if (lane == 0) {
        red[w] = ssim_loc;
        red[4 + w] = l1_loc;
    }
    __syncthreads();
    if (tid == 0) {
        float ss = red[0] + red[1] + red[2] + red[3];
        float ll = red[4] + red[5] + red[6] + red[7];
        int bid = blockIdx.x + NTX * (blockIdx.y + NTY * blockIdx.z);
        partials[bid] = ss;
        partials[NBLOCKS + bid] = ll;
    }
}

__global__ __launch_bounds__(1024)
void finalize_kernel(const float* __restrict__ partials, float* __restrict__ out) {
    __shared__ double rs[16], rl[16];
    const int tid = threadIdx.x;
    double ss = 0.0, ll = 0.0;
    for (int i = tid; i < NBLOCKS; i += 1024) {
        ss += (double)partials[i];
        ll += (double)partials[NBLOCKS + i];
    }
    #pragma unroll
    for (int off = 32; off > 0; off >>= 1) {
        ss += __shfl_down(ss, off);
        ll += __shfl_down(ll, off);
    }
    int wave = tid >> 6, lane = tid & 63;
    if (lane == 0) { rs[wave] = ss; rl[wave] = ll; }
    __syncthreads();
    if (tid == 0) {
        double sst = 0.0, llt = 0.0;
        #pragma unroll
        for (int w = 0; w < 16; ++w) { sst += rs[w]; llt += rl[w]; }
        double invn = 1.0 / (double)NPIX;
        out[0] = (float)(llt * invn + (1.0 - sst * invn));
    }
}

extern "C" void kernel_launch(void* const* d_in, const int* in_sizes, int n_in,
                              void* d_out, int out_size, void* d_ws, size_t ws_size,
                              hipStream_t stream) {
    const float* x = (const float*)d_in[0];   // outputs
    const float* y = (const float*)d_in[1];   // labels
    float* out = (float*)d_out;
    float* partials = (float*)d_ws;           // 2*NBLOCKS*4 = 49,152 B

    dim3 grid(NTX, NTY, NIMG);
    ssim_tile_kernel<<<grid, dim3(256), 0, stream>>>(x, y, partials);
    finalize_kernel<<<1, dim3(1024), 0, stream>>>(partials, out);
}

// Round 7
// 136.987 us; speedup vs baseline: 1.0086x; 1.0054x over previous
//
#include <hip/hip_runtime.h>
#include <hip/hip_bf16.h>
#include <math.h>

#define IMG 512
#define TW 64                     // output tile width
#define TH 32                     // output tile height
#define NTX 8                     // 512/64
#define NTY 16                    // 512/32
#define NIMG 48                   // 16*3
#define NBLOCKS (NTX * NTY * NIMG)   // 6144
#define NPIX (16LL * 3 * 512 * 512)

#define C1F 0.0001f
#define C2F 0.0009f

// R7: hard-forced memory-level parallelism.
// R6 post-mortem: sched_barrier(0) fences were defeated BEFORE the machine
// scheduler — IR-level sinking moved the pure loads to their uses (the
// intrinsic is inaccessiblemem-only, invisible to IR passes), so VGPR
// stayed 52 and the wave still ran ~12 serialized ~900-cyc round trips
// (Little's law: 9.8 waves/CU resident, 96 waves/CU, 115k cyc => ~11.5k
// cyc wave lifetime vs ~800 cyc issue). Fix with IR-proof tools:
//  - 12 volatile inline-asm global_load_dwordx4 (SGPR base + clamped
//    32-bit voffset): cannot sink, cannot reorder, issue back-to-back.
//  - ONE asm "s_waitcnt vmcnt(0)" that TIES all 12 results as "+v"
//    operands: every consumer data-depends on it — nothing consumes a
//    load dest before the drain, at any compiler level (rule #18 made
//    airtight). sched_barrier(0) after, belt-and-suspenders.
//  - B-fragment LDS gather sits in the latency window (can't cross the
//    volatile asms above or the memory-clobber waitcnt below).
//  - OOB: clamped (always in-bounds) addresses + post-wait zero-select
//    (~48 cndmask/thread — VALU is at ~12.5%/SIMD, free). No template
//    split needed; numerics identical to R4-R6.
// Tripwires: VGPR < 70 => asm defeated (void). WRITE_SIZE >> 1 MB =>
// spill (R3 failure mode). Both clean => this round is a valid test of
// the latency-exposure theory.

typedef __attribute__((ext_vector_type(4))) short short4v;
typedef __attribute__((ext_vector_type(8))) short short8;
typedef __attribute__((ext_vector_type(4))) float float4v;
typedef __attribute__((ext_vector_type(2))) unsigned uint2v;
typedef __attribute__((ext_vector_type(4))) unsigned uint4v;

// 16x16x16 bf16 MFMA (device-verified _1k builtin on gfx950; host parse stub).
__device__ __forceinline__ float4v mfma16(short4v a, short4v b, float4v c) {
#if defined(__HIP_DEVICE_COMPILE__)
    return __builtin_amdgcn_mfma_f32_16x16x16bf16_1k(a, b, c, 0, 0, 0);
#else
    return c;   // host stub — never executed
#endif
}

// Volatile asm 16B global loads: SGPR base + 32-bit byte voffset.
__device__ __forceinline__ float4v gload16(const float* base, int boff) {
    float4v r;
#if defined(__HIP_DEVICE_COMPILE__)
    asm volatile("global_load_dwordx4 %0, %1, %2"
                 : "=v"(r) : "v"(boff), "s"(base));
#else
    r = (float4v){0.f, 0.f, 0.f, 0.f};
#endif
    return r;
}
__device__ __forceinline__ float4v gload16o(const float* base, int boff) {
    float4v r;
#if defined(__HIP_DEVICE_COMPILE__)
    asm volatile("global_load_dwordx4 %0, %1, %2 offset:16"
                 : "=v"(r) : "v"(boff), "s"(base));
#else
    r = (float4v){0.f, 0.f, 0.f, 0.f};
#endif
    return r;
}

// Gaussian window (sigma=1.5, ws=11), normalized (double-derived literals).
#define GW0 0.00102838f
#define GW1 0.00759877f
#define GW2 0.03600077f
#define GW3 0.10936069f
#define GW4 0.21300539f
#define GW5 0.26601172f

__device__ __forceinline__ unsigned short f2bf(float f) {
    unsigned u = __builtin_bit_cast(unsigned, f);
    u += 0x7FFF + ((u >> 16) & 1);            // RNE
    return (unsigned short)(u >> 16);
}
__device__ __forceinline__ unsigned pk2(float a, float b) {
    __hip_bfloat162 h = __float22bfloat162_rn(make_float2(a, b));
    unsigned u;
    __builtin_memcpy(&u, &h, 4);
    return u;
}

#define BC4(U) __builtin_bit_cast(short4v, U)

// Consume one rg: in-register bf16 channel build, 4 H-conv MFMAs into named
// uint2v destinations, owned-region L1 (q in {1,2}, srow in [5,36]).
#define CONSUME_RG(XF0, XF1, YF0, YF1, SROW_EXPR, DSTX, DSTY, DSTS, DSTP)      \
    {                                                                          \
        const int srow_ = (SROW_EXPR);                                         \
        uint4v ux_ = (uint4v){pk2(XF0[0], XF0[1]), pk2(XF0[2], XF0[3]),        \
                              pk2(XF1[0], XF1[1]), pk2(XF1[2], XF1[3])};       \
        uint4v uy_ = (uint4v){pk2(YF0[0], YF0[1]), pk2(YF0[2], YF0[3]),        \
                              pk2(YF1[0], YF1[1]), pk2(YF1[2], YF1[3])};       \
        uint4v u2_ = (uint4v){                                                 \
            pk2(fmaf(XF0[0],XF0[0],YF0[0]*YF0[0]),                             \
                fmaf(XF0[1],XF0[1],YF0[1]*YF0[1])),                            \
            pk2(fmaf(XF0[2],XF0[2],YF0[2]*YF0[2]),                             \
                fmaf(XF0[3],XF0[3],YF0[3]*YF0[3])),                            \
            pk2(fmaf(XF1[0],XF1[0],YF1[0]*YF1[0]),                             \
                fmaf(XF1[1],XF1[1],YF1[1]*YF1[1])),                            \
            pk2(fmaf(XF1[2],XF1[2],YF1[2]*YF1[2]),                             \
                fmaf(XF1[3],XF1[3],YF1[3]*YF1[3]))};                           \
        uint4v u3_ = (uint4v){                                                 \
            pk2(XF0[0]*YF0[0], XF0[1]*YF0[1]),                                 \
            pk2(XF0[2]*YF0[2], XF0[3]*YF0[3]),                                 \
            pk2(XF1[0]*YF1[0], XF1[1]*YF1[1]),                                 \
            pk2(XF1[2]*YF1[2], XF1[3]*YF1[3])};                                \
        float4v d_;                                                            \
        d_ = __builtin_amdgcn_mfma_f32_16x16x32_bf16(                          \
                 __builtin_bit_cast(short8, ux_), bh, zero4, 0, 0, 0);         \
        DSTX = (uint2v){pk2(d_[0], d_[1]), pk2(d_[2], d_[3])};                 \
        d_ = __builtin_amdgcn_mfma_f32_16x16x32_bf16(                          \
                 __builtin_bit_cast(short8, uy_), bh, zero4, 0, 0, 0);         \
        DSTY = (uint2v){pk2(d_[0], d_[1]), pk2(d_[2], d_[3])};                 \
        d_ = __builtin_amdgcn_mfma_f32_16x16x32_bf16(                          \
                 __builtin_bit_cast(short8, u2_), bh, zero4, 0, 0, 0);         \
        DSTS = (uint2v){pk2(d_[0], d_[1]), pk2(d_[2], d_[3])};                 \
        d_ = __builtin_amdgcn_mfma_f32_16x16x32_bf16(                          \
                 __builtin_bit_cast(short8, u3_), bh, zero4, 0, 0, 0);         \
        DSTP = (uint2v){pk2(d_[0], d_[1]), pk2(d_[2], d_[3])};                 \
        if ((unsigned)(q - 1) <= 1u && (unsigned)(srow_ - 5) <= 31u)           \
            l1_loc += fabsf(XF0[0]-YF0[0])+fabsf(XF0[1]-YF0[1])                \
                    + fabsf(XF0[2]-YF0[2])+fabsf(XF0[3]-YF0[3])                \
                    + fabsf(XF1[0]-YF1[0])+fabsf(XF1[1]-YF1[1])                \
                    + fabsf(XF1[2]-YF1[2])+fabsf(XF1[3]-YF1[3]);               \
    }

// SSIM epilogue over one float4v set.
#define SSIM_ACC(M1, M2, EE, PP)                                               \
    _Pragma("unroll")                                                          \
    for (int r_ = 0; r_ < 4; ++r_) {                                           \
        float mu1 = (M1)[r_], mu2 = (M2)[r_];                                  \
        float e   = (EE)[r_], e12 = (PP)[r_];                                  \
        float p = mu1 * mu2;                                                   \
        float s = fmaf(mu1, mu1, mu2 * mu2);                                   \
        float num1 = fmaf(2.f, p, C1F);                                        \
        float num2 = fmaf(2.f, e12 - p, C2F);                                  \
        float den1 = s + C1F;                                                  \
        float den2 = (e - s) + C2F;                                            \
        ssim_loc = fmaf(num1 * num2,                                           \
                        __builtin_amdgcn_rcpf(den1 * den2), ssim_loc);         \
    }

__global__ __launch_bounds__(256, 4)
void ssim_tile_kernel(const float* __restrict__ xg, const float* __restrict__ yg,
                      float* __restrict__ partials) {
    __shared__ unsigned short gwtbl[16];            // bf16 taps, [11..15]=0
    __shared__ float red[8];

    const int tid  = threadIdx.x;
    const int lane = tid & 63;
    const int w    = tid >> 6;        // wave 0..3 = colgroup
    const int q    = lane >> 4;       // quad 0..3
    const int n16  = lane & 15;

    const int img = blockIdx.z;
    const int r00  = blockIdx.y * TH - 5;   // global row of staged-coords row 0
    const int c00a = blockIdx.x * TW - 8;   // global col of staged-coords col 0
    const float* __restrict__ xi = xg + (size_t)img * (IMG * IMG);
    const float* __restrict__ yi = yg + (size_t)img * (IMG * IMG);

    // ---- bf16 Gaussian tap table (compile-time-folded constants) ----
    if (tid < 16) {
        const float gwf[11] = {GW0, GW1, GW2, GW3, GW4, GW5, GW4, GW3, GW2, GW1, GW0};
        unsigned short v = 0;
        #pragma unroll
        for (int t = 0; t < 11; ++t)
            if (tid == t) v = f2bf(gwf[t]);
        gwtbl[tid] = v;
    }
    __syncthreads();   // publish gwtbl (no memory in flight yet)

    // ---- Addresses: clamped (always in-bounds), ok-masks for zero-select --
    const int cbase = c00a + w * 16 + q * 8;
    const bool colok = (unsigned)cbase < 512u;
    const int cc = min(max(cbase, 0), 504);

    const int grA = r00 + n16;
    const int grB = r00 + 16 + n16;
    const int grC = r00 + min(32 + n16, 41);   // rows 42..47: zero v-taps
    const bool okA = colok && (unsigned)grA < 512u;
    const bool okB = colok && (unsigned)grB < 512u;
    const bool okC = colok && (unsigned)grC < 512u;
    const int offA = (min(max(grA, 0), 511) * IMG + cc) * 4;
    const int offB = (min(max(grB, 0), 511) * IMG + cc) * 4;
    const int offC = (min(max(grC, 0), 511) * IMG + cc) * 4;

    // ---- Phase 1: 12 volatile asm loads, back-to-back ----
    float4v xA0 = gload16 (xi, offA), xA1 = gload16o(xi, offA);
    float4v yA0 = gload16 (yi, offA), yA1 = gload16o(yi, offA);
    float4v xB0 = gload16 (xi, offB), xB1 = gload16o(xi, offB);
    float4v yB0 = gload16 (yi, offB), yB1 = gload16o(yi, offB);
    float4v xC0 = gload16 (xi, offC), xC1 = gload16o(xi, offC);
    float4v yC0 = gload16 (yi, offC), yC1 = gload16o(yi, offC);

    // ---- Phase 2: B fragments from gwtbl (sits in the latency window:
    //      can't hoist above volatile asm, can't sink below memory-clobber
    //      waitcnt) ----
    // h (K=32): Bh[k][n] = g[k-n-3], k = q*8+j
    // v chunk0 (K=16): Bv0[k][n] = g[k-n]; chunk1: Bv1[k][n] = g[k+16-n]
    short8 bh;
    short4v bv0, bv1;
    {
        int baseh = q * 8 - n16 - 3;
        #pragma unroll
        for (int j = 0; j < 8; ++j)
            bh[j] = (short)gwtbl[min((unsigned)(baseh + j), 15u)];
        int base0 = q * 4 - n16, base1 = q * 4 + 16 - n16;
        #pragma unroll
        for (int j = 0; j < 4; ++j) {
            bv0[j] = (short)gwtbl[min((unsigned)(base0 + j), 15u)];
            bv1[j] = (short)gwtbl[min((unsigned)(base1 + j), 15u)];
        }
    }

    // ---- Single drain point: ties all 12 results, so every consumer
    //      data-depends on this asm — cannot execute before the wait. ----
#if defined(__HIP_DEVICE_COMPILE__)
    asm volatile("s_waitcnt vmcnt(0)"
                 : "+v"(xA0), "+v"(xA1), "+v"(yA0), "+v"(yA1),
                   "+v"(xB0), "+v"(xB1), "+v"(yB0), "+v"(yB1),
                   "+v"(xC0), "+v"(xC1), "+v"(yC0), "+v"(yC1)
                 :: "memory");
    __builtin_amdgcn_sched_barrier(0);
#endif

    // ---- Zero-select OOB (matches reference zero padding) ----
    const float4v zero4 = {0.f, 0.f, 0.f, 0.f};
    if (!okA) { xA0 = zero4; xA1 = zero4; yA0 = zero4; yA1 = zero4; }
    if (!okB) { xB0 = zero4; xB1 = zero4; yB0 = zero4; yB1 = zero4; }
    if (!okC) { xC0 = zero4; xC1 = zero4; yC0 = zero4; yC1 = zero4; }

    // ---- Phase 3: consume (pk2 + 4 H-conv MFMAs per rg) ----
    float l1_loc = 0.f;
    uint2v d0x, d0y, d0s, d0p;
    uint2v e1x, e1y, e1s, e1p;
    uint2v f2x, f2y, f2s, f2p;
    CONSUME_RG(xA0, xA1, yA0, yA1, n16,      d0x, d0y, d0s, d0p)
    CONSUME_RG(xB0, xB1, yB0, yB1, 16 + n16, e1x, e1y, e1s, e1p)
    CONSUME_RG(xC0, xC1, yC0, yC1, 32 + n16, f2x, f2y, f2s, f2p)

    // ---- V-conv: acc = D1[rgp]·Bv0 + D1[rgp+1]·Bv1 (chained x16 MFMAs).
    //      Output: lane (q,n16) = out row rgp*16+n16, out cols w*16+q*4+r. --
    float ssim_loc = 0.f;
    {   // rgp = 0
        float4v am1 = mfma16(BC4(d0x), bv0, mfma16(BC4(e1x), bv1, zero4));
        float4v am2 = mfma16(BC4(d0y), bv0, mfma16(BC4(e1y), bv1, zero4));
        float4v ae  = mfma16(BC4(d0s), bv0, mfma16(BC4(e1s), bv1, zero4));
        float4v ap  = mfma16(BC4(d0p), bv0, mfma16(BC4(e1p), bv1, zero4));
        SSIM_ACC(am1, am2, ae, ap)
    }
    {   // rgp = 1
        float4v bm1 = mfma16(BC4(e1x), bv0, mfma16(BC4(f2x), bv1, zero4));
        float4v bm2 = mfma16(BC4(e1y), bv0, mfma16(BC4(f2y), bv1, zero4));
        float4v be  = mfma16(BC4(e1s), bv0, mfma16(BC4(f2s), bv1, zero4));
        float4v bp  = mfma16(BC4(e1p), bv0, mfma16(BC4(f2p), bv1, zero4));
        SSIM_ACC(bm1, bm2, be, bp)
    }

    // ---- Block reduction ----
    #pragma unroll
    for (int off = 32; off > 0; off >>= 1) {
        ssim_loc += __shfl_down(ssim_loc, off);
        l1_loc   += __shfl_down(l1_loc, off);
    }
    if (lane == 0) {
        red[w] = ssim_loc;
        red[4 + w] = l1_loc;
    }
    __syncthreads();
    if (tid == 0) {
        float ss = red[0] + red[1] + red[2] + red[3];
        float ll = red[4] + red[5] + red[6] + red[7];
        int bid = blockIdx.x + NTX * (blockIdx.y + NTY * blockIdx.z);
        partials[bid] = ss;
        partials[NBLOCKS + bid] = ll;
    }
}

__global__ __launch_bounds__(1024)
void finalize_kernel(const float* __restrict__ partials, float* __restrict__ out) {
    __shared__ double rs[16], rl[16];
    const int tid = threadIdx.x;
    double ss = 0.0, ll = 0.0;
    for (int i = tid; i < NBLOCKS; i += 1024) {
        ss += (double)partials[i];
        ll += (double)partials[NBLOCKS + i];
    }
    #pragma unroll
    for (int off = 32; off > 0; off >>= 1) {
        ss += __shfl_down(ss, off);
        ll += __shfl_down(ll, off);
    }
    int wave = tid >> 6, lane = tid & 63;
    if (lane == 0) { rs[wave] = ss; rl[wave] = ll; }
    __syncthreads();
    if (tid == 0) {
        double sst = 0.0, llt = 0.0;
        #pragma unroll
        for (int w = 0; w < 16; ++w) { sst += rs[w]; llt += rl[w]; }
        double invn = 1.0 / (double)NPIX;
        out[0] = (float)(llt * invn + (1.0 - sst * invn));
    }
}

extern "C" void kernel_launch(void* const* d_in, const int* in_sizes, int n_in,
                              void* d_out, int out_size, void* d_ws, size_t ws_size,
                              hipStream_t stream) {
    const float* x = (const float*)d_in[0];   // outputs
    const float* y = (const float*)d_in[1];   // labels
    float* out = (float*)d_out;
    float* partials = (float*)d_ws;           // 2*NBLOCKS*4 = 49,152 B

    dim3 grid(NTX, NTY, NIMG);
    ssim_tile_kernel<<<grid, dim3(256), 0, stream>>>(x, y, partials);
    finalize_kernel<<<1, dim3(1024), 0, stream>>>(partials, out);
}